// Round 1
// baseline (322.405 us; speedup 1.0000x reference)
//
#include <hip/hip_runtime.h>
#include <hip/hip_fp16.h>

#define HID 32
#define BN 64          // nodes per bucket -> NBr = ceil(100000/64) = 1563
#define NBPAD 1792     // 7 * 256, padded bucket count for binscatter scan
#define BSTRIDE 2432   // per-bucket edge capacity: mean 2048 + 8.5 sigma
#define CHUNK 4096     // edges per binscatter chunk
#define EPT 8          // edges/thread in binscatter (CHUNK/512)
#define SPT 10         // max per-thread items in sort/build streams (2560 >= BSTRIDE)

__device__ __forceinline__ float lrelu(float x) { return x > 0.0f ? x : 0.2f * x; }

// ---------------- transform (layer-1 dense) ----------------

__global__ void k_transform1(const float* __restrict__ x,
                             const float* __restrict__ W1,
                             const float* __restrict__ att_src,
                             const float* __restrict__ att_dst,
                             __half* __restrict__ hh,
                             float* __restrict__ a_s,
                             float* __restrict__ a_d,
                             int* __restrict__ cursor, int N)
{
    int tid = blockIdx.x * blockDim.x + threadIdx.x;
    if (tid < NBPAD) cursor[tid] = 0;
    int n = tid >> 5, f = tid & 31;
    if (n >= N) return;
    float x0 = x[n * 3 + 0], x1 = x[n * 3 + 1], x2 = x[n * 3 + 2];
    float hv = x0 * W1[f] + x1 * W1[HID + f] + x2 * W1[2 * HID + f];
    hh[(size_t)n * HID + f] = __float2half(hv);
    float as = hv * att_src[f];
    float ad = hv * att_dst[f];
    #pragma unroll
    for (int m = 16; m >= 1; m >>= 1) {
        as += __shfl_xor(as, m, 32);
        ad += __shfl_xor(ad, m, 32);
    }
    if (f == 0) { a_s[n] = as; a_d[n] = ad; }
}

// ---------------- binscatter: edges -> per-bucket runs ----------------
// Register-carried edges (one src/dst read pass), LDS-staged sort by bucket
// so global writes are coalesced runs. 39 KB LDS -> 4 blocks/CU.

__global__ void __launch_bounds__(512) k_binscatter(const int* __restrict__ src,
        const int* __restrict__ dst, int* __restrict__ cursor,
        unsigned int* __restrict__ packed, int E)
{
    __shared__ int stage[CHUNK];              // 16 KB
    __shared__ unsigned short sbid[CHUNK];    // 8 KB
    __shared__ int lidx[NBPAD];               // 7 KB: hist -> excl -> running idx
    __shared__ int lbase[NBPAD];              // 7 KB: global base - excl
    __shared__ int arr[256];                  // 1 KB

    int t = threadIdx.x;
    int base = blockIdx.x * CHUNK;
    int cnt = E - base; if (cnt > CHUNK) cnt = CHUNK;

    for (int i = t; i < NBPAD; i += 512) lidx[i] = 0;
    __syncthreads();

    int myb[EPT]; unsigned mypk[EPT];
    #pragma unroll
    for (int u = 0; u < EPT; ++u) {
        int i = t + u * 512;
        myb[u] = -1;
        if (i < cnt) {
            int d = dst[base + i];
            int s = src[base + i];
            int b = d >> 6;
            myb[u] = b;
            mypk[u] = (unsigned)s | ((unsigned)(d & 63) << 17);
            atomicAdd(&lidx[b], 1);
        }
    }
    __syncthreads();

    int c[7]; int ssum = 0; int b0 = 7 * t;
    if (t < 256) {
        #pragma unroll
        for (int k = 0; k < 7; ++k) { c[k] = lidx[b0 + k]; ssum += c[k]; }
        arr[t] = ssum;
    }
    __syncthreads();
    for (int o = 1; o < 256; o <<= 1) {
        int v = (t < 256 && t >= o) ? arr[t - o] : 0;
        __syncthreads();
        if (t < 256) arr[t] += v;
        __syncthreads();
    }
    if (t < 256) {
        int run = arr[t] - ssum;
        #pragma unroll
        for (int k = 0; k < 7; ++k) {
            int ck = c[k];
            lidx[b0 + k] = run;
            if (ck) {
                int gb = (b0 + k) * BSTRIDE + atomicAdd(&cursor[b0 + k], ck);
                lbase[b0 + k] = gb - run;
                for (int i2 = 0; i2 < ck; ++i2)
                    sbid[run + i2] = (unsigned short)(b0 + k);
            }
            run += ck;
        }
    }
    __syncthreads();

    #pragma unroll
    for (int u = 0; u < EPT; ++u) {
        if (myb[u] >= 0) {
            int idx = atomicAdd(&lidx[myb[u]], 1);
            stage[idx] = (int)mypk[u];
        }
    }
    __syncthreads();

    for (int i = t; i < cnt; i += 512) {
        int b = sbid[i];
        int gpos = lbase[b] + i;
        if (gpos < (b + 1) * BSTRIDE) packed[gpos] = (unsigned)stage[i];
    }
}

// ---------------- sort: per-bucket counting sort (in-place) + CSR meta ----
// Done ONCE; both agg layers reuse the node-sorted order.

__global__ void __launch_bounds__(256) k_sort(const int* __restrict__ cursor,
        unsigned int* __restrict__ packed, int* __restrict__ nmeta, int N)
{
    __shared__ int hist[64];
    __shared__ int scn[64];
    __shared__ int stage[BSTRIDE];            // 9.5 KB

    int bk = blockIdx.x, t = threadIdx.x;
    int cnt = cursor[bk]; if (cnt > BSTRIDE) cnt = BSTRIDE;
    if (t < 64) hist[t] = 0;
    __syncthreads();

    unsigned pk[SPT];
    #pragma unroll
    for (int u = 0; u < SPT; ++u) {
        int i = t + u * 256;
        if (i < cnt) {
            pk[u] = packed[(size_t)bk * BSTRIDE + i];
            atomicAdd(&hist[(pk[u] >> 17) & 63], 1);
        }
    }
    __syncthreads();

    if (t < 64) scn[t] = hist[t];
    __syncthreads();
    for (int o = 1; o < 64; o <<= 1) {
        int v = (t < 64 && t >= o) ? scn[t - o] : 0;
        __syncthreads();
        if (t < 64) scn[t] += v;
        __syncthreads();
    }
    if (t < 64) {
        int cdeg = hist[t];
        int ex = scn[t] - cdeg;
        hist[t] = ex;                          // repurpose as running index
        int n = bk * BN + t;
        if (n < N) nmeta[n] = ex | (cdeg << 16);
    }
    __syncthreads();

    #pragma unroll
    for (int u = 0; u < SPT; ++u) {
        int i = t + u * 256;
        if (i < cnt) {
            int idx = atomicAdd(&hist[(pk[u] >> 17) & 63], 1);
            stage[idx] = (int)pk[u];
        }
    }
    __syncthreads();

    for (int i = t; i < cnt; i += 256)
        packed[(size_t)bk * BSTRIDE + i] = (unsigned)stage[i];
}

// ---------------- agg building blocks ----------------

struct AggSM {
    int2  lpair[BSTRIDE];   // 19 KB: .x = src node, .y = exp bits (node-sorted)
    float adT[BN];
    float asT[BN];
    int   meta[BN];         // off | deg<<16
};

// single coalesced streaming pass: no atomics, no scan, coalesced LDS writes
template<int BLK>
__device__ __forceinline__ void build_stream(AggSM& S,
        const unsigned int* __restrict__ pk, int cnt,
        const float* __restrict__ a_s, const float* __restrict__ a_d,
        const int* __restrict__ nmeta, int nodeBase, int N)
{
    int t = threadIdx.x;
    if (t < BN) {
        int n = nodeBase + t;
        bool ok = n < N;
        S.meta[t] = ok ? nmeta[n] : 0;
        S.adT[t]  = ok ? a_d[n] : 0.0f;
        S.asT[t]  = ok ? a_s[n] : 0.0f;
    }
    __syncthreads();
    #pragma unroll
    for (int u = 0; u < SPT; ++u) {
        int i = t + u * BLK;
        if (i < cnt) {
            unsigned p = pk[i];
            int sv = (int)(p & 0x1FFFF);
            int dl = (p >> 17) & 63;
            float e = __expf(lrelu(a_s[sv] + S.adT[dl]));
            S.lpair[i] = make_int2(sv, __float_as_int(e));
        }
    }
    __syncthreads();
}

// agg inner loop: 8 lanes/node, 4 features/lane, 8B dwordx2 gathers, unroll x8
__device__ __forceinline__ void agg_node8(const __half* __restrict__ hh,
        float exs, const float* __restrict__ b, int n, int f,
        const int2* lpair, int off, int dg,
        float& v0, float& v1, float& v2, float& v3)
{
    uint2 us = *(const uint2*)(hh + (size_t)n * HID + 4 * f);
    float2 s01 = __half22float2(*(__half2*)&us.x);
    float2 s23 = __half22float2(*(__half2*)&us.y);
    float den = exs;
    float a0 = exs * s01.x, a1 = exs * s01.y, a2 = exs * s23.x, a3 = exs * s23.y;

    int j = 0;
    for (; j + 8 <= dg; j += 8) {
        int2 p[8]; uint2 uu[8];
        #pragma unroll
        for (int q = 0; q < 8; ++q) p[q] = lpair[off + j + q];
        #pragma unroll
        for (int q = 0; q < 8; ++q)
            uu[q] = *(const uint2*)(hh + (size_t)p[q].x * HID + 4 * f);
        #pragma unroll
        for (int q = 0; q < 8; ++q) {
            float e = __int_as_float(p[q].y);
            float2 qa = __half22float2(*(__half2*)&uu[q].x);
            float2 qb = __half22float2(*(__half2*)&uu[q].y);
            den += e;
            a0 = fmaf(e, qa.x, a0); a1 = fmaf(e, qa.y, a1);
            a2 = fmaf(e, qb.x, a2); a3 = fmaf(e, qb.y, a3);
        }
    }
    for (; j < dg; ++j) {
        int2 pp = lpair[off + j];
        uint2 uu = *(const uint2*)(hh + (size_t)pp.x * HID + 4 * f);
        float e = __int_as_float(pp.y);
        float2 qa = __half22float2(*(__half2*)&uu.x);
        float2 qb = __half22float2(*(__half2*)&uu.y);
        den += e;
        a0 = fmaf(e, qa.x, a0); a1 = fmaf(e, qa.y, a1);
        a2 = fmaf(e, qb.x, a2); a3 = fmaf(e, qb.y, a3);
    }
    float inv = 1.0f / (den + 1e-16f);
    float4 bb = *(const float4*)(b + 4 * f);
    v0 = fmaxf(a0 * inv + bb.x, 0.0f);
    v1 = fmaxf(a1 * inv + bb.y, 0.0f);
    v2 = fmaxf(a2 * inv + bb.z, 0.0f);
    v3 = fmaxf(a3 * inv + bb.w, 0.0f);
}

// layer-1 epilogue: W2 transform + layer-2 attention halves (8-lane groups)
__device__ __forceinline__ void epi_mid8(int n, int f,
        float v0, float v1, float v2, float v3,
        const float* __restrict__ W2, const float* __restrict__ as2w,
        const float* __restrict__ ad2w,
        __half* __restrict__ hh_out, float* __restrict__ as_out,
        float* __restrict__ ad_out)
{
    float h0 = 0.0f, h1 = 0.0f, h2 = 0.0f, h3 = 0.0f;
    #pragma unroll
    for (int k = 0; k < 8; ++k) {
        float aa[4];
        aa[0] = __shfl(v0, k, 8);
        aa[1] = __shfl(v1, k, 8);
        aa[2] = __shfl(v2, k, 8);
        aa[3] = __shfl(v3, k, 8);
        const float* wr = W2 + (4 * k) * HID + 4 * f;
        #pragma unroll
        for (int c = 0; c < 4; ++c) {
            float4 w = *(const float4*)(wr + c * HID);
            h0 = fmaf(aa[c], w.x, h0);
            h1 = fmaf(aa[c], w.y, h1);
            h2 = fmaf(aa[c], w.z, h2);
            h3 = fmaf(aa[c], w.w, h3);
        }
    }
    __half2 o01 = __floats2half2_rn(h0, h1);
    __half2 o23 = __floats2half2_rn(h2, h3);
    uint2 st;
    st.x = *(unsigned*)&o01;
    st.y = *(unsigned*)&o23;
    *(uint2*)(hh_out + (size_t)n * HID + 4 * f) = st;

    float4 asw = *(const float4*)(as2w + 4 * f);
    float4 adw = *(const float4*)(ad2w + 4 * f);
    float as = h0 * asw.x + h1 * asw.y + h2 * asw.z + h3 * asw.w;
    float ad = h0 * adw.x + h1 * adw.y + h2 * adw.z + h3 * adw.w;
    #pragma unroll
    for (int m2 = 4; m2 >= 1; m2 >>= 1) {
        as += __shfl_xor(as, m2, 8);
        ad += __shfl_xor(ad, m2, 8);
    }
    if (f == 0) { as_out[n] = as; ad_out[n] = ad; }
}

// ---------------- agg kernels ----------------

__global__ void __launch_bounds__(256, 8) k_agg_mid(const __half* __restrict__ hh,
        const float* __restrict__ a_s, const float* __restrict__ a_d,
        const int* __restrict__ cursor, const unsigned int* __restrict__ packed,
        const int* __restrict__ nmeta,
        const float* __restrict__ b1, const float* __restrict__ W2,
        const float* __restrict__ as2w, const float* __restrict__ ad2w,
        __half* __restrict__ hh_out, float* __restrict__ as_out,
        float* __restrict__ ad_out, int N)
{
    __shared__ AggSM S;
    int bk = blockIdx.x, t = threadIdx.x;
    int cnt = cursor[bk]; if (cnt > BSTRIDE) cnt = BSTRIDE;
    build_stream<256>(S, packed + (size_t)bk * BSTRIDE, cnt, a_s, a_d,
                      nmeta, bk * BN, N);
    int g = t >> 3, f = t & 7;
    for (int dl = g; dl < BN; dl += 32) {
        int n = bk * BN + dl;
        if (n >= N) continue;
        int m = S.meta[dl];
        int off = m & 0xFFFF, dg = m >> 16;
        float exs = __expf(lrelu(S.asT[dl] + S.adT[dl]));
        float v0, v1, v2, v3;
        agg_node8(hh, exs, b1, n, f, S.lpair, off, dg, v0, v1, v2, v3);
        epi_mid8(n, f, v0, v1, v2, v3, W2, as2w, ad2w, hh_out, as_out, ad_out);
    }
}

__global__ void __launch_bounds__(256, 8) k_agg_out(const __half* __restrict__ hh,
        const float* __restrict__ a_s, const float* __restrict__ a_d,
        const int* __restrict__ cursor, const unsigned int* __restrict__ packed,
        const int* __restrict__ nmeta,
        const float* __restrict__ b2, const float* __restrict__ Wl,
        const float* __restrict__ bl, float* __restrict__ out, int N)
{
    __shared__ AggSM S;
    int bk = blockIdx.x, t = threadIdx.x;
    int cnt = cursor[bk]; if (cnt > BSTRIDE) cnt = BSTRIDE;
    build_stream<256>(S, packed + (size_t)bk * BSTRIDE, cnt, a_s, a_d,
                      nmeta, bk * BN, N);
    int g = t >> 3, f = t & 7;
    for (int dl = g; dl < BN; dl += 32) {
        int n = bk * BN + dl;
        if (n >= N) continue;
        int m = S.meta[dl];
        int off = m & 0xFFFF, dg = m >> 16;
        float exs = __expf(lrelu(S.asT[dl] + S.adT[dl]));
        float v0, v1, v2, v3;
        agg_node8(hh, exs, b2, n, f, S.lpair, off, dg, v0, v1, v2, v3);
        float4 wl = *(const float4*)(Wl + 4 * f);
        float y = v0 * wl.x + v1 * wl.y + v2 * wl.z + v3 * wl.w;
        #pragma unroll
        for (int m2 = 4; m2 >= 1; m2 >>= 1)
            y += __shfl_xor(y, m2, 8);
        if (f == 0) out[n] = y + bl[0];
    }
}

// ---------------- host ----------------

extern "C" void kernel_launch(void* const* d_in, const int* in_sizes, int n_in,
                              void* d_out, int out_size, void* d_ws, size_t ws_size,
                              hipStream_t stream)
{
    const float* x        = (const float*)d_in[0];
    const int*   eidx     = (const int*)d_in[1];
    const float* W1       = (const float*)d_in[2];
    const float* att_src1 = (const float*)d_in[3];
    const float* att_dst1 = (const float*)d_in[4];
    const float* b1       = (const float*)d_in[5];
    const float* W2       = (const float*)d_in[6];
    const float* att_src2 = (const float*)d_in[7];
    const float* att_dst2 = (const float*)d_in[8];
    const float* b2       = (const float*)d_in[9];
    const float* Wl       = (const float*)d_in[10];
    const float* bl       = (const float*)d_in[11];
    float* out = (float*)d_out;

    int N = in_sizes[0] / 3;
    int E = in_sizes[1] / 2;
    const int* src = eidx;
    const int* dst = eidx + E;
    int NBr = (N + BN - 1) / BN;   // 1563

    size_t szNHh = (size_t)N * HID * 2;          // 6.4 MB
    size_t szN4  = (size_t)N * 4;
    size_t szPK  = (size_t)NBr * BSTRIDE * 4;    // 15.2 MB

    char* ws = (char*)d_ws;
    __half* h1h    = (__half*)ws; ws += szNHh;
    __half* h2h    = (__half*)ws; ws += szNHh;
    unsigned int* packed = (unsigned int*)ws; ws += szPK;
    float*  a_s1   = (float*)ws;  ws += szN4;
    float*  a_d1   = (float*)ws;  ws += szN4;
    float*  a_s2   = (float*)ws;  ws += szN4;
    float*  a_d2   = (float*)ws;  ws += szN4;
    int*    nmeta  = (int*)ws;    ws += szN4;
    int*    cursor = (int*)ws;    ws += NBPAD * 4;

    const int B = 256;
    int gridNode32 = (N * HID + B - 1) / B;
    int gridBin    = (E + CHUNK - 1) / CHUNK;

    k_transform1<<<gridNode32, B, 0, stream>>>(x, W1, att_src1, att_dst1,
                                               h1h, a_s1, a_d1, cursor, N);
    k_binscatter<<<gridBin, 512, 0, stream>>>(src, dst, cursor, packed, E);
    k_sort<<<NBr, 256, 0, stream>>>(cursor, packed, nmeta, N);
    k_agg_mid<<<NBr, 256, 0, stream>>>(h1h, a_s1, a_d1, cursor, packed, nmeta,
                                       b1, W2, att_src2, att_dst2,
                                       h2h, a_s2, a_d2, N);
    k_agg_out<<<NBr, 256, 0, stream>>>(h2h, a_s2, a_d2, cursor, packed, nmeta,
                                       b2, Wl, bl, out, N);
}

// Round 2
// 260.457 us; speedup vs baseline: 1.2378x; 1.2378x over previous
//
#include <hip/hip_runtime.h>
#include <hip/hip_fp16.h>

#define HID 32
#define BN 131         // nodes per bucket -> NBr = ceil(100000/131) = 764
#define NBPAD 768      // padded bucket arrays (3 per thread in binscatter scan)
#define BSTRIDE 4608   // per-bucket edge capacity: mean 4194 + 6.4 sigma
#define CHUNK 4096     // edges per binscatter chunk
#define SPT_B 9        // build stream: ceil(4608/512)
#define SPT_S 18       // sort stream:  ceil(4608/256)

__device__ __forceinline__ float lrelu(float x) { return x > 0.0f ? x : 0.2f * x; }

// ---------------- transform (layer-1 dense) ----------------

__global__ void k_transform1(const float* __restrict__ x,
                             const float* __restrict__ W1,
                             const float* __restrict__ att_src,
                             const float* __restrict__ att_dst,
                             __half* __restrict__ hh,
                             float* __restrict__ a_s,
                             float* __restrict__ a_d,
                             int* __restrict__ cursor, int N)
{
    int tid = blockIdx.x * blockDim.x + threadIdx.x;
    if (tid < NBPAD) cursor[tid] = 0;
    int n = tid >> 5, f = tid & 31;
    if (n >= N) return;
    float x0 = x[n * 3 + 0], x1 = x[n * 3 + 1], x2 = x[n * 3 + 2];
    float hv = x0 * W1[f] + x1 * W1[HID + f] + x2 * W1[2 * HID + f];
    hh[(size_t)n * HID + f] = __float2half(hv);
    float as = hv * att_src[f];
    float ad = hv * att_dst[f];
    #pragma unroll
    for (int m = 16; m >= 1; m >>= 1) {
        as += __shfl_xor(as, m, 32);
        ad += __shfl_xor(ad, m, 32);
    }
    if (f == 0) { a_s[n] = as; a_d[n] = ad; }
}

// ---------------- binscatter (R0-proven form, verbatim geometry) ----------
// LDS-staged sort by bucket so global writes are coalesced runs.
// Cursor atomics issued in ONE parallel pass (not serialized).

struct BinSM {
    int stage[CHUNK];                 // 16 KB
    unsigned short sbid[CHUNK];       // 8 KB
    int lhist[NBPAD], lexcl[NBPAD], lbase[NBPAD], lcur[NBPAD];  // 12 KB
    int arr[256];                     // 1 KB
};

__global__ void __launch_bounds__(512) k_binscatter(const int* __restrict__ src,
        const int* __restrict__ dst, int* __restrict__ cursor,
        unsigned int* __restrict__ packed, int NBr, int E)
{
    __shared__ BinSM S;
    const int BLK = 512;
    int t = threadIdx.x;
    int base = blockIdx.x * CHUNK;
    for (int i = t; i < NBPAD; i += BLK) { S.lhist[i] = 0; S.lcur[i] = 0; }
    __syncthreads();
    int cnt = E - base; if (cnt > CHUNK) cnt = CHUNK;
    for (int i = t; i < cnt; i += BLK)
        atomicAdd(&S.lhist[dst[base + i] / BN], 1);
    __syncthreads();
    int b0 = 3 * t;
    int c0 = 0, c1 = 0, c2 = 0, s = 0;
    if (t < 256) {
        c0 = S.lhist[b0]; c1 = S.lhist[b0 + 1]; c2 = S.lhist[b0 + 2];
        s = c0 + c1 + c2;
        S.arr[t] = s;
    }
    __syncthreads();
    for (int o = 1; o < 256; o <<= 1) {
        int v = (t < 256 && t >= o) ? S.arr[t - o] : 0;
        __syncthreads();
        if (t < 256) S.arr[t] += v;
        __syncthreads();
    }
    if (t < 256) {
        int ex = S.arr[t] - s;
        int e0 = ex, e1 = ex + c0, e2 = ex + c0 + c1;
        S.lexcl[b0] = e0; S.lexcl[b0 + 1] = e1; S.lexcl[b0 + 2] = e2;
        for (int i = 0; i < c0; ++i) S.sbid[e0 + i] = (unsigned short)b0;
        for (int i = 0; i < c1; ++i) S.sbid[e1 + i] = (unsigned short)(b0 + 1);
        for (int i = 0; i < c2; ++i) S.sbid[e2 + i] = (unsigned short)(b0 + 2);
    }
    for (int b = t; b < NBr; b += BLK)
        if (S.lhist[b]) S.lbase[b] = b * BSTRIDE + atomicAdd(&cursor[b], S.lhist[b]);
    __syncthreads();
    for (int i = t; i < cnt; i += BLK) {
        int d = dst[base + i];
        int sv = src[base + i];
        int b = d / BN;
        int dl = d - b * BN;
        int idx = S.lexcl[b] + atomicAdd(&S.lcur[b], 1);
        S.stage[idx] = (int)((unsigned)sv | ((unsigned)dl << 17));
    }
    __syncthreads();
    for (int i = t; i < cnt; i += BLK) {
        int b = S.sbid[i];
        int gpos = S.lbase[b] + (i - S.lexcl[b]);
        if (gpos < (b + 1) * BSTRIDE)
            packed[gpos] = (unsigned)S.stage[i];
    }
}

// ---------------- sort: per-bucket counting sort (in-place) + CSR meta ----
// Done ONCE; both agg layers reuse the node-sorted order.

__global__ void __launch_bounds__(256) k_sort(const int* __restrict__ cursor,
        unsigned int* __restrict__ packed, int* __restrict__ nmeta, int N)
{
    __shared__ int hist[256];
    __shared__ int scn[256];
    __shared__ int stage[BSTRIDE];            // 18 KB

    int bk = blockIdx.x, t = threadIdx.x;
    int cnt = cursor[bk]; if (cnt > BSTRIDE) cnt = BSTRIDE;
    hist[t] = 0;
    __syncthreads();

    unsigned pk[SPT_S];
    #pragma unroll
    for (int u = 0; u < SPT_S; ++u) {
        int i = t + u * 256;
        if (i < cnt) {
            pk[u] = packed[(size_t)bk * BSTRIDE + i];
            atomicAdd(&hist[(pk[u] >> 17) & 255], 1);
        }
    }
    __syncthreads();

    scn[t] = hist[t];
    __syncthreads();
    for (int o = 1; o < 256; o <<= 1) {
        int v = (t >= o) ? scn[t - o] : 0;
        __syncthreads();
        scn[t] += v;
        __syncthreads();
    }
    int cdeg = hist[t];
    int ex = scn[t] - cdeg;
    hist[t] = ex;                              // repurpose as running index
    if (t < BN) {
        int n = bk * BN + t;
        if (n < N) nmeta[n] = ex | (cdeg << 16);
    }
    __syncthreads();

    #pragma unroll
    for (int u = 0; u < SPT_S; ++u) {
        int i = t + u * 256;
        if (i < cnt) {
            int idx = atomicAdd(&hist[(pk[u] >> 17) & 255], 1);
            stage[idx] = (int)pk[u];
        }
    }
    __syncthreads();

    for (int i = t; i < cnt; i += 256)
        packed[(size_t)bk * BSTRIDE + i] = (unsigned)stage[i];
}

// ---------------- agg building blocks ----------------

struct AggSM {
    int2  lpair[BSTRIDE];   // 36.9 KB: .x = src node, .y = exp bits (node-sorted)
    float adT[BN];
    float asT[BN];
    int   meta[BN];         // off | deg<<16
};

// single coalesced streaming pass: no atomics, no scan, coalesced LDS writes
__device__ __forceinline__ void build_stream(AggSM& S,
        const unsigned int* __restrict__ pk, int cnt,
        const float* __restrict__ a_s, const float* __restrict__ a_d,
        const int* __restrict__ nmeta, int nodeBase, int N)
{
    int t = threadIdx.x;
    if (t < BN) {
        int n = nodeBase + t;
        bool ok = n < N;
        S.meta[t] = ok ? nmeta[n] : 0;
        S.adT[t]  = ok ? a_d[n] : 0.0f;
        S.asT[t]  = ok ? a_s[n] : 0.0f;
    }
    __syncthreads();
    #pragma unroll
    for (int u = 0; u < SPT_B; ++u) {
        int i = t + u * 512;
        if (i < cnt) {
            unsigned p = pk[i];
            int sv = (int)(p & 0x1FFFF);
            int dl = (p >> 17) & 255;
            float e = __expf(lrelu(a_s[sv] + S.adT[dl]));
            S.lpair[i] = make_int2(sv, __float_as_int(e));
        }
    }
    __syncthreads();
}

// agg inner loop: 8 lanes/node, 4 features/lane, 8B dwordx2 gathers, unroll x8
__device__ __forceinline__ void agg_node8(const __half* __restrict__ hh,
        float exs, const float* __restrict__ b, int n, int f,
        const int2* lpair, int off, int dg,
        float& v0, float& v1, float& v2, float& v3)
{
    uint2 us = *(const uint2*)(hh + (size_t)n * HID + 4 * f);
    float2 s01 = __half22float2(*(__half2*)&us.x);
    float2 s23 = __half22float2(*(__half2*)&us.y);
    float den = exs;
    float a0 = exs * s01.x, a1 = exs * s01.y, a2 = exs * s23.x, a3 = exs * s23.y;

    int j = 0;
    for (; j + 8 <= dg; j += 8) {
        int2 p[8]; uint2 uu[8];
        #pragma unroll
        for (int q = 0; q < 8; ++q) p[q] = lpair[off + j + q];
        #pragma unroll
        for (int q = 0; q < 8; ++q)
            uu[q] = *(const uint2*)(hh + (size_t)p[q].x * HID + 4 * f);
        #pragma unroll
        for (int q = 0; q < 8; ++q) {
            float e = __int_as_float(p[q].y);
            float2 qa = __half22float2(*(__half2*)&uu[q].x);
            float2 qb = __half22float2(*(__half2*)&uu[q].y);
            den += e;
            a0 = fmaf(e, qa.x, a0); a1 = fmaf(e, qa.y, a1);
            a2 = fmaf(e, qb.x, a2); a3 = fmaf(e, qb.y, a3);
        }
    }
    for (; j < dg; ++j) {
        int2 pp = lpair[off + j];
        uint2 uu = *(const uint2*)(hh + (size_t)pp.x * HID + 4 * f);
        float e = __int_as_float(pp.y);
        float2 qa = __half22float2(*(__half2*)&uu.x);
        float2 qb = __half22float2(*(__half2*)&uu.y);
        den += e;
        a0 = fmaf(e, qa.x, a0); a1 = fmaf(e, qa.y, a1);
        a2 = fmaf(e, qb.x, a2); a3 = fmaf(e, qb.y, a3);
    }
    float inv = 1.0f / (den + 1e-16f);
    float4 bb = *(const float4*)(b + 4 * f);
    v0 = fmaxf(a0 * inv + bb.x, 0.0f);
    v1 = fmaxf(a1 * inv + bb.y, 0.0f);
    v2 = fmaxf(a2 * inv + bb.z, 0.0f);
    v3 = fmaxf(a3 * inv + bb.w, 0.0f);
}

// layer-1 epilogue: W2 transform + layer-2 attention halves (8-lane groups)
__device__ __forceinline__ void epi_mid8(int n, int f,
        float v0, float v1, float v2, float v3,
        const float* __restrict__ W2, const float* __restrict__ as2w,
        const float* __restrict__ ad2w,
        __half* __restrict__ hh_out, float* __restrict__ as_out,
        float* __restrict__ ad_out)
{
    float h0 = 0.0f, h1 = 0.0f, h2 = 0.0f, h3 = 0.0f;
    #pragma unroll
    for (int k = 0; k < 8; ++k) {
        float aa[4];
        aa[0] = __shfl(v0, k, 8);
        aa[1] = __shfl(v1, k, 8);
        aa[2] = __shfl(v2, k, 8);
        aa[3] = __shfl(v3, k, 8);
        const float* wr = W2 + (4 * k) * HID + 4 * f;
        #pragma unroll
        for (int c = 0; c < 4; ++c) {
            float4 w = *(const float4*)(wr + c * HID);
            h0 = fmaf(aa[c], w.x, h0);
            h1 = fmaf(aa[c], w.y, h1);
            h2 = fmaf(aa[c], w.z, h2);
            h3 = fmaf(aa[c], w.w, h3);
        }
    }
    __half2 o01 = __floats2half2_rn(h0, h1);
    __half2 o23 = __floats2half2_rn(h2, h3);
    uint2 st;
    st.x = *(unsigned*)&o01;
    st.y = *(unsigned*)&o23;
    *(uint2*)(hh_out + (size_t)n * HID + 4 * f) = st;

    float4 asw = *(const float4*)(as2w + 4 * f);
    float4 adw = *(const float4*)(ad2w + 4 * f);
    float as = h0 * asw.x + h1 * asw.y + h2 * asw.z + h3 * asw.w;
    float ad = h0 * adw.x + h1 * adw.y + h2 * adw.z + h3 * adw.w;
    #pragma unroll
    for (int m2 = 4; m2 >= 1; m2 >>= 1) {
        as += __shfl_xor(as, m2, 8);
        ad += __shfl_xor(ad, m2, 8);
    }
    if (f == 0) { as_out[n] = as; ad_out[n] = ad; }
}

// ---------------- agg kernels ----------------

__global__ void __launch_bounds__(512) k_agg_mid(const __half* __restrict__ hh,
        const float* __restrict__ a_s, const float* __restrict__ a_d,
        const int* __restrict__ cursor, const unsigned int* __restrict__ packed,
        const int* __restrict__ nmeta,
        const float* __restrict__ b1, const float* __restrict__ W2,
        const float* __restrict__ as2w, const float* __restrict__ ad2w,
        __half* __restrict__ hh_out, float* __restrict__ as_out,
        float* __restrict__ ad_out, int N)
{
    __shared__ AggSM S;
    int bk = blockIdx.x, t = threadIdx.x;
    int cnt = cursor[bk]; if (cnt > BSTRIDE) cnt = BSTRIDE;
    build_stream(S, packed + (size_t)bk * BSTRIDE, cnt, a_s, a_d,
                 nmeta, bk * BN, N);
    int g = t >> 3, f = t & 7;
    for (int dl = g; dl < BN; dl += 64) {
        int n = bk * BN + dl;
        if (n >= N) continue;
        int m = S.meta[dl];
        int off = m & 0xFFFF, dg = m >> 16;
        float exs = __expf(lrelu(S.asT[dl] + S.adT[dl]));
        float v0, v1, v2, v3;
        agg_node8(hh, exs, b1, n, f, S.lpair, off, dg, v0, v1, v2, v3);
        epi_mid8(n, f, v0, v1, v2, v3, W2, as2w, ad2w, hh_out, as_out, ad_out);
    }
}

__global__ void __launch_bounds__(512) k_agg_out(const __half* __restrict__ hh,
        const float* __restrict__ a_s, const float* __restrict__ a_d,
        const int* __restrict__ cursor, const unsigned int* __restrict__ packed,
        const int* __restrict__ nmeta,
        const float* __restrict__ b2, const float* __restrict__ Wl,
        const float* __restrict__ bl, float* __restrict__ out, int N)
{
    __shared__ AggSM S;
    int bk = blockIdx.x, t = threadIdx.x;
    int cnt = cursor[bk]; if (cnt > BSTRIDE) cnt = BSTRIDE;
    build_stream(S, packed + (size_t)bk * BSTRIDE, cnt, a_s, a_d,
                 nmeta, bk * BN, N);
    int g = t >> 3, f = t & 7;
    for (int dl = g; dl < BN; dl += 64) {
        int n = bk * BN + dl;
        if (n >= N) continue;
        int m = S.meta[dl];
        int off = m & 0xFFFF, dg = m >> 16;
        float exs = __expf(lrelu(S.asT[dl] + S.adT[dl]));
        float v0, v1, v2, v3;
        agg_node8(hh, exs, b2, n, f, S.lpair, off, dg, v0, v1, v2, v3);
        float4 wl = *(const float4*)(Wl + 4 * f);
        float y = v0 * wl.x + v1 * wl.y + v2 * wl.z + v3 * wl.w;
        #pragma unroll
        for (int m2 = 4; m2 >= 1; m2 >>= 1)
            y += __shfl_xor(y, m2, 8);
        if (f == 0) out[n] = y + bl[0];
    }
}

// ---------------- host ----------------

extern "C" void kernel_launch(void* const* d_in, const int* in_sizes, int n_in,
                              void* d_out, int out_size, void* d_ws, size_t ws_size,
                              hipStream_t stream)
{
    const float* x        = (const float*)d_in[0];
    const int*   eidx     = (const int*)d_in[1];
    const float* W1       = (const float*)d_in[2];
    const float* att_src1 = (const float*)d_in[3];
    const float* att_dst1 = (const float*)d_in[4];
    const float* b1       = (const float*)d_in[5];
    const float* W2       = (const float*)d_in[6];
    const float* att_src2 = (const float*)d_in[7];
    const float* att_dst2 = (const float*)d_in[8];
    const float* b2       = (const float*)d_in[9];
    const float* Wl       = (const float*)d_in[10];
    const float* bl       = (const float*)d_in[11];
    float* out = (float*)d_out;

    int N = in_sizes[0] / 3;
    int E = in_sizes[1] / 2;
    const int* src = eidx;
    const int* dst = eidx + E;
    int NBr = (N + BN - 1) / BN;   // 764

    size_t szNHh = (size_t)N * HID * 2;          // 6.4 MB
    size_t szN4  = (size_t)N * 4;
    size_t szPK  = (size_t)NBr * BSTRIDE * 4;    // 14.1 MB

    char* ws = (char*)d_ws;
    __half* h1h    = (__half*)ws; ws += szNHh;
    __half* h2h    = (__half*)ws; ws += szNHh;
    unsigned int* packed = (unsigned int*)ws; ws += szPK;
    float*  a_s1   = (float*)ws;  ws += szN4;
    float*  a_d1   = (float*)ws;  ws += szN4;
    float*  a_s2   = (float*)ws;  ws += szN4;
    float*  a_d2   = (float*)ws;  ws += szN4;
    int*    nmeta  = (int*)ws;    ws += szN4;
    int*    cursor = (int*)ws;    ws += NBPAD * 4;

    const int B = 256;
    int gridNode32 = (N * HID + B - 1) / B;
    int gridBin    = (E + CHUNK - 1) / CHUNK;

    k_transform1<<<gridNode32, B, 0, stream>>>(x, W1, att_src1, att_dst1,
                                               h1h, a_s1, a_d1, cursor, N);
    k_binscatter<<<gridBin, 512, 0, stream>>>(src, dst, cursor, packed, NBr, E);
    k_sort<<<NBr, 256, 0, stream>>>(cursor, packed, nmeta, N);
    k_agg_mid<<<NBr, 512, 0, stream>>>(h1h, a_s1, a_d1, cursor, packed, nmeta,
                                       b1, W2, att_src2, att_dst2,
                                       h2h, a_s2, a_d2, N);
    k_agg_out<<<NBr, 512, 0, stream>>>(h2h, a_s2, a_d2, cursor, packed, nmeta,
                                       b2, Wl, bl, out, N);
}